// Round 4
// baseline (395.413 us; speedup 1.0000x reference)
//
#include <hip/hip_runtime.h>
#include <hip/hip_bf16.h>

typedef __bf16 bf16;
typedef bf16 bf16x8 __attribute__((ext_vector_type(8)));
typedef bf16 bf16x4 __attribute__((ext_vector_type(4)));
typedef short s16x4 __attribute__((ext_vector_type(4)));
typedef float f32x4 __attribute__((ext_vector_type(4)));

#define SCALE 0.17677669529663687f  // 1/sqrt(32)

// LDS (bf16 elems): xb/o [64][200] @0 ; vt per-wave [32][68] @12800+w*2176
// f32 proj-out overlay [64][200] f32 over everything (51,200B <= 51,712B)
#define OFF_V 12800
#define SMEM_ELEMS 25856   // 51,712 B

#if defined(__has_builtin)
#if __has_builtin(__builtin_amdgcn_mfma_f32_16x16x16bf16_1k)
#define HAS_MFMA16 1
#endif
#endif

// ---------------- prep kernel (unchanged, validated) ----------------
__global__ void wattn_prep(const float* __restrict__ wq, const float* __restrict__ wkv,
                           const float* __restrict__ bias_table, const float* __restrict__ proj_w,
                           bf16* __restrict__ wqkvT, bf16* __restrict__ projT,
                           float* __restrict__ biasB)
{
    int t = blockIdx.x * 256 + threadIdx.x;
    if (t < 110592) {                       // wqkvT[n][k] = W[k][n]
        int n = t / 192, k = t % 192;
        float v = (n < 192) ? wq[k * 192 + n] : wkv[k * 384 + (n - 192)];
        wqkvT[t] = (bf16)v;
    } else if (t < 147456) {                // projT[n][k] = proj_w[k][n]
        int e = t - 110592;
        int n = e / 192, k = e % 192;
        projT[e] = (bf16)proj_w[k * 192 + n];
    } else if (t < 172032) {                // biasB[h][m>>2][n][m&3]
        int e = t - 147456;
        int h  = e >> 12;
        int mb = (e >> 8) & 15;
        int n  = (e >> 2) & 63;
        int mr = e & 3;
        int m  = mb * 4 + mr;
        int idx = ((n & 7) - (m & 7) + 7) * 15 + ((n >> 3) - (m >> 3) + 7);
        biasB[e] = bias_table[idx * 6 + h];
    }
}

#if !defined(HAS_MFMA16)
// fallback: build K=32 frag from two D-layout bf16x4 tiles via shuffles
__device__ __forceinline__ bf16x8 build8(bf16x4 t0, bf16x4 t1, int li, int gi) {
    union { bf16x4 v; unsigned u[2]; } a0, a1;
    a0.v = t0; a1.v = t1;
    int b = li + 32 * (gi & 1);
    unsigned l0  = __shfl(a0.u[0], b),      l1  = __shfl(a0.u[1], b);
    unsigned l0h = __shfl(a0.u[0], b + 16), l1h = __shfl(a0.u[1], b + 16);
    unsigned h0  = __shfl(a1.u[0], b),      h1  = __shfl(a1.u[1], b);
    unsigned h0h = __shfl(a1.u[0], b + 16), h1h = __shfl(a1.u[1], b + 16);
    bool hi = (gi & 2);
    union { bf16x8 v8; unsigned u[4]; } r;
    r.u[0] = hi ? h0 : l0;   r.u[1] = hi ? h1 : l1;
    r.u[2] = hi ? h0h : l0h; r.u[3] = hi ? h1h : l1h;
    return r.v8;
}
#endif

// ---------------- fused main kernel: one window per block, one head per wave ----------------
__global__ __launch_bounds__(384, 3)
void wattn_main(const float* __restrict__ x, const bf16* __restrict__ wqkvT,
                const float* __restrict__ bq, const float* __restrict__ bkv,
                const bf16* __restrict__ projT, const float* __restrict__ biasB,
                const float* __restrict__ proj_b, float* __restrict__ outg)
{
    __shared__ __align__(16) bf16 smem[SMEM_ELEMS];
    const int tid = threadIdx.x;
    const int li  = tid & 15;
    const int gi  = (tid >> 4) & 3;
    const int w   = tid >> 6;        // wave = head, 0..5
    const int win = blockIdx.x;

    bf16* xb = smem;                          // x -> (dead) -> attn-out [n][c]
    bf16* vt = smem + OFF_V + w * 2176;       // per-wave private v^T [32][68]

    const int srow = tid / 48, scol = tid % 48;
    const f32x4 fz = {0.f, 0.f, 0.f, 0.f};

    // ---- stage x: f32 global -> bf16 LDS [64][200] ----
    {
        const float4* xg = (const float4*)(x + (size_t)win * 12288);
#pragma unroll
        for (int i = 0; i < 8; ++i) {
            float4 p = xg[(srow + 8 * i) * 48 + scol];
            bf16x4 v; v[0]=(bf16)p.x; v[1]=(bf16)p.y; v[2]=(bf16)p.z; v[3]=(bf16)p.w;
            *(bf16x4*)&xb[(srow + 8 * i) * 200 + scol * 4] = v;
        }
    }
    __syncthreads();                                     // B1

    // ================= QKV^T pass A: q,k (acc 4x4 = 64 AGPR peak) =================
    bf16x4 qf[2][4], kf[2][4];
    {
        f32x4 aqk[4][4];
#pragma unroll
        for (int j = 0; j < 4; ++j)
#pragma unroll
            for (int c = 0; c < 4; ++c) aqk[j][c] = fz;
#pragma unroll
        for (int kk = 0; kk < 6; ++kk) {
            bf16x8 bx[4], aw[4];
#pragma unroll
            for (int c = 0; c < 4; ++c)
                bx[c] = *(const bf16x8*)&xb[(c * 16 + li) * 200 + kk * 32 + gi * 8];
#pragma unroll
            for (int j = 0; j < 4; ++j) {
                int T = (j < 2) ? (2 * w + j) : (12 + 2 * w + (j - 2));
                aw[j] = *(const bf16x8*)&wqkvT[(size_t)(T * 16 + li) * 192 + kk * 32 + gi * 8];
            }
#pragma unroll
            for (int j = 0; j < 4; ++j)
#pragma unroll
                for (int c = 0; c < 4; ++c)
                    aqk[j][c] = __builtin_amdgcn_mfma_f32_16x16x32_bf16(aw[j], bx[c], aqk[j][c], 0, 0, 0);
        }
        // epilogue A: bias + leaky (+SCALE for q) -> registers
        f32x4 bjq0 = *(const f32x4*)&bq[32 * w + 4 * gi];
        f32x4 bjq1 = *(const f32x4*)&bq[32 * w + 16 + 4 * gi];
        f32x4 bjk0 = *(const f32x4*)&bkv[32 * w + 4 * gi];
        f32x4 bjk1 = *(const f32x4*)&bkv[32 * w + 16 + 4 * gi];
#pragma unroll
        for (int j = 0; j < 2; ++j)
#pragma unroll
            for (int c = 0; c < 4; ++c) {
                bf16x4 rq, rk;
#pragma unroll
                for (int rg = 0; rg < 4; ++rg) {
                    float tq = aqk[j][c][rg]     + (j ? bjq1[rg] : bjq0[rg]);
                    float tk = aqk[2 + j][c][rg] + (j ? bjk1[rg] : bjk0[rg]);
                    tq = (fmaxf(tq, 0.f) + 0.2f * fminf(tq, 0.f)) * SCALE;
                    tk =  fmaxf(tk, 0.f) + 0.2f * fminf(tk, 0.f);
                    rq[rg] = (bf16)tq;
                    rk[rg] = (bf16)tk;
                }
                qf[j][c] = rq;
                kf[j][c] = rk;
            }
    }

    // ================= QKV^T pass B: v (acc 2x4 = 32 AGPR) =================
    {
        f32x4 av_[2][4];
#pragma unroll
        for (int j = 0; j < 2; ++j)
#pragma unroll
            for (int c = 0; c < 4; ++c) av_[j][c] = fz;
#pragma unroll
        for (int kk = 0; kk < 6; ++kk) {
            bf16x8 bx[4], aw[2];
#pragma unroll
            for (int c = 0; c < 4; ++c)
                bx[c] = *(const bf16x8*)&xb[(c * 16 + li) * 200 + kk * 32 + gi * 8];
#pragma unroll
            for (int j = 0; j < 2; ++j)
                aw[j] = *(const bf16x8*)&wqkvT[(size_t)((24 + 2 * w + j) * 16 + li) * 192 + kk * 32 + gi * 8];
#pragma unroll
            for (int j = 0; j < 2; ++j)
#pragma unroll
                for (int c = 0; c < 4; ++c)
                    av_[j][c] = __builtin_amdgcn_mfma_f32_16x16x32_bf16(aw[j], bx[c], av_[j][c], 0, 0, 0);
        }
        __syncthreads();                                 // B2 (all x reads done)
        f32x4 bjv0 = *(const f32x4*)&bkv[192 + 32 * w + 4 * gi];
        f32x4 bjv1 = *(const f32x4*)&bkv[192 + 32 * w + 16 + 4 * gi];
#pragma unroll
        for (int j = 0; j < 2; ++j)
#pragma unroll
            for (int c = 0; c < 4; ++c)
#pragma unroll
                for (int rg = 0; rg < 4; ++rg) {
                    float t = av_[j][c][rg] + (j ? bjv1[rg] : bjv0[rg]);
                    t = fmaxf(t, 0.f) + 0.2f * fminf(t, 0.f);
                    vt[(16 * j + 4 * gi + rg) * 68 + c * 16 + li] = (bf16)t;
                }
    }

    // ---- QK^T straight from registers: S^T[m][n] tiles s[cm][cn] ----
    f32x4 s[4][4];
#if defined(HAS_MFMA16)
#pragma unroll
    for (int cm = 0; cm < 4; ++cm)
#pragma unroll
        for (int cn = 0; cn < 4; ++cn) {
            f32x4 t = __builtin_amdgcn_mfma_f32_16x16x16bf16_1k(
                __builtin_bit_cast(s16x4, kf[0][cm]), __builtin_bit_cast(s16x4, qf[0][cn]), fz, 0, 0, 0);
            s[cm][cn] = __builtin_amdgcn_mfma_f32_16x16x16bf16_1k(
                __builtin_bit_cast(s16x4, kf[1][cm]), __builtin_bit_cast(s16x4, qf[1][cn]), t, 0, 0, 0);
        }
#else
    {
        bf16x8 ka[4], qb[4];
#pragma unroll
        for (int cm = 0; cm < 4; ++cm) ka[cm] = build8(kf[0][cm], kf[1][cm], li, gi);
#pragma unroll
        for (int cn = 0; cn < 4; ++cn) qb[cn] = build8(qf[0][cn], qf[1][cn], li, gi);
#pragma unroll
        for (int cm = 0; cm < 4; ++cm)
#pragma unroll
            for (int cn = 0; cn < 4; ++cn)
                s[cm][cn] = __builtin_amdgcn_mfma_f32_16x16x32_bf16(ka[cm], qb[cn], fz, 0, 0, 0);
    }
#endif

    // ---- + bias, softmax over keys, P -> bf16 regs ----
    float rs[4];
    bf16x4 pb[4][4];
#pragma unroll
    for (int cn = 0; cn < 4; ++cn) {
        float m_ = -1e30f;
#pragma unroll
        for (int cm = 0; cm < 4; ++cm) {
            s[cm][cn] += *(const f32x4*)&biasB[w * 4096 + (4 * cm + gi) * 256 + (16 * cn + li) * 4];
#pragma unroll
            for (int rg = 0; rg < 4; ++rg) m_ = fmaxf(m_, s[cm][cn][rg]);
        }
        m_ = fmaxf(m_, __shfl_xor(m_, 16));
        m_ = fmaxf(m_, __shfl_xor(m_, 32));
        float ss = 0.f;
#pragma unroll
        for (int cm = 0; cm < 4; ++cm) {
            bf16x4 r;
#pragma unroll
            for (int rg = 0; rg < 4; ++rg) {
                float p = __expf(s[cm][cn][rg] - m_);
                ss += p;
                r[rg] = (bf16)p;
            }
            pb[cm][cn] = r;
        }
        ss += __shfl_xor(ss, 16);
        ss += __shfl_xor(ss, 32);
        rs[cn] = 1.f / ss;
    }

    // ---- PV: out^T[d][n] = v^T (LDS A-frags) x P^T (register B-frags) ----
    f32x4 o[2][4];
#pragma unroll
    for (int dt = 0; dt < 2; ++dt) {
#if defined(HAS_MFMA16)
        s16x4 av[4];
#pragma unroll
        for (int ks = 0; ks < 4; ++ks)
            av[ks] = *(const s16x4*)&vt[(dt * 16 + li) * 68 + ks * 16 + gi * 4];
#pragma unroll
        for (int cn = 0; cn < 4; ++cn) {
            f32x4 t = fz;
#pragma unroll
            for (int ks = 0; ks < 4; ++ks)
                t = __builtin_amdgcn_mfma_f32_16x16x16bf16_1k(
                        av[ks], __builtin_bit_cast(s16x4, pb[ks][cn]), t, 0, 0, 0);
            o[dt][cn] = t;
        }
#else
        bf16x8 av2[2];
#pragma unroll
        for (int c = 0; c < 2; ++c)
            av2[c] = *(const bf16x8*)&vt[(dt * 16 + li) * 68 + c * 32 + gi * 8];
#pragma unroll
        for (int cn = 0; cn < 4; ++cn) {
            f32x4 t = fz;
#pragma unroll
            for (int c = 0; c < 2; ++c)
                t = __builtin_amdgcn_mfma_f32_16x16x32_bf16(
                        av2[c], build8(pb[2 * c][cn], pb[2 * c + 1][cn], li, gi), t, 0, 0, 0);
            o[dt][cn] = t;
        }
#endif
    }
    // normalize + write attn-out [n][c] into xb (x dead since B2)
#pragma unroll
    for (int dt = 0; dt < 2; ++dt)
#pragma unroll
        for (int cn = 0; cn < 4; ++cn) {
            bf16x4 r;
#pragma unroll
            for (int rg = 0; rg < 4; ++rg) r[rg] = (bf16)(o[dt][cn][rg] * rs[cn]);
            *(bf16x4*)&xb[(cn * 16 + li) * 200 + 32 * w + 16 * dt + 4 * gi] = r;
        }
    __syncthreads();                                     // B3 (attn-out complete)

    // ---- proj: y^T[c][n] = Wp^T (A) * o^T (B from xb) ----
    f32x4 pa[2][4];
#pragma unroll
    for (int ct = 0; ct < 2; ++ct)
#pragma unroll
        for (int cn = 0; cn < 4; ++cn) pa[ct][cn] = fz;
#pragma unroll
    for (int kk = 0; kk < 6; ++kk) {
        bf16x8 bo[4], awp[2];
#pragma unroll
        for (int cn = 0; cn < 4; ++cn)
            bo[cn] = *(const bf16x8*)&xb[(cn * 16 + li) * 200 + kk * 32 + gi * 8];
#pragma unroll
        for (int ct = 0; ct < 2; ++ct)
            awp[ct] = *(const bf16x8*)&projT[(size_t)((2 * w + ct) * 16 + li) * 192 + kk * 32 + gi * 8];
#pragma unroll
        for (int ct = 0; ct < 2; ++ct)
#pragma unroll
            for (int cn = 0; cn < 4; ++cn)
                pa[ct][cn] = __builtin_amdgcn_mfma_f32_16x16x32_bf16(awp[ct], bo[cn], pa[ct][cn], 0, 0, 0);
    }
    __syncthreads();                                     // B4 (all o reads done)

    // ---- + proj bias -> f32 overlay [64][200] over whole smem ----
    {
        float* of = (float*)smem;
        f32x4 pb0 = *(const f32x4*)&proj_b[32 * w + 4 * gi];
        f32x4 pb1 = *(const f32x4*)&proj_b[32 * w + 16 + 4 * gi];
#pragma unroll
        for (int ct = 0; ct < 2; ++ct)
#pragma unroll
            for (int cn = 0; cn < 4; ++cn) {
                f32x4 y = pa[ct][cn];
#pragma unroll
                for (int rg = 0; rg < 4; ++rg) y[rg] += (ct ? pb1[rg] : pb0[rg]);
                *(f32x4*)&of[(cn * 16 + li) * 200 + 32 * w + 16 * ct + 4 * gi] = y;
            }
    }
    __syncthreads();                                     // B5

    // ---- coalesced copy-out ----
    {
        const float* ofr = (const float*)smem;
        float4* og = (float4*)(outg + (size_t)win * 12288);
#pragma unroll
        for (int i = 0; i < 8; ++i)
            og[(srow + 8 * i) * 48 + scol] = *(const float4*)&ofr[(srow + 8 * i) * 200 + scol * 4];
    }
}

extern "C" void kernel_launch(void* const* d_in, const int* in_sizes, int n_in,
                              void* d_out, int out_size, void* d_ws, size_t ws_size,
                              hipStream_t stream)
{
    const float* x          = (const float*)d_in[0];
    const float* wq         = (const float*)d_in[1];
    const float* bq         = (const float*)d_in[2];
    const float* wkv        = (const float*)d_in[3];
    const float* bkv        = (const float*)d_in[4];
    const float* bias_table = (const float*)d_in[5];
    const float* proj_w     = (const float*)d_in[6];
    const float* proj_b     = (const float*)d_in[7];
    float* out = (float*)d_out;

    int B = in_sizes[0] / (64 * 192);

    bf16*  wqkvT = (bf16*)d_ws;
    bf16*  projT = (bf16*)((char*)d_ws + 221184);
    float* biasB = (float*)((char*)d_ws + 294912);

    wattn_prep<<<672, 256, 0, stream>>>(wq, wkv, bias_table, proj_w, wqkvT, projT, biasB);

    wattn_main<<<B, 384, 0, stream>>>(x, wqkvT, bq, bkv, projT, biasB, proj_b, out);
}

// Round 5
// 266.739 us; speedup vs baseline: 1.4824x; 1.4824x over previous
//
#include <hip/hip_runtime.h>
#include <hip/hip_bf16.h>

typedef __bf16 bf16;
typedef bf16 bf16x8 __attribute__((ext_vector_type(8)));
typedef bf16 bf16x4 __attribute__((ext_vector_type(4)));
typedef short s16x4 __attribute__((ext_vector_type(4)));
typedef float f32x4 __attribute__((ext_vector_type(4)));

#define SCALE 0.17677669529663687f  // 1/sqrt(32)

// LDS: xb bf16 [64][208] @0 (26,624B, x -> attn-out) ;
//      f32 out-stage [64][196] @13312 elems (50,176B). total 76,800B -> 2 blocks/CU.
#define XSTR 208
#define FSTR 196
#define OFF_F 13312                 // bf16 units
#define SMEM_ELEMS 38400

#if defined(__has_builtin)
#if __has_builtin(__builtin_amdgcn_mfma_f32_16x16x16bf16_1k)
#define HAS_MFMA16 1
#endif
#endif

// ---------------- prep kernel (unchanged, validated) ----------------
__global__ void wattn_prep(const float* __restrict__ wq, const float* __restrict__ wkv,
                           const float* __restrict__ bias_table, const float* __restrict__ proj_w,
                           bf16* __restrict__ wqkvT, bf16* __restrict__ projT,
                           float* __restrict__ biasB)
{
    int t = blockIdx.x * 256 + threadIdx.x;
    if (t < 110592) {                       // wqkvT[n][k] = W[k][n]
        int n = t / 192, k = t % 192;
        float v = (n < 192) ? wq[k * 192 + n] : wkv[k * 384 + (n - 192)];
        wqkvT[t] = (bf16)v;
    } else if (t < 147456) {                // projT[n][k] = proj_w[k][n]
        int e = t - 110592;
        int n = e / 192, k = e % 192;
        projT[e] = (bf16)proj_w[k * 192 + n];
    } else if (t < 172032) {                // biasB[h][m>>2][n][m&3]
        int e = t - 147456;
        int h  = e >> 12;
        int mb = (e >> 8) & 15;
        int n  = (e >> 2) & 63;
        int mr = e & 3;
        int m  = mb * 4 + mr;
        int idx = ((n & 7) - (m & 7) + 7) * 15 + ((n >> 3) - (m >> 3) + 7);
        biasB[e] = bias_table[idx * 6 + h];
    }
}

#if !defined(HAS_MFMA16)
// fallback: build K=32 frag from two D-layout bf16x4 tiles via shuffles
__device__ __forceinline__ bf16x8 build8(bf16x4 t0, bf16x4 t1, int li, int gi) {
    union { bf16x4 v; unsigned u[2]; } a0, a1;
    a0.v = t0; a1.v = t1;
    int b = li + 32 * (gi & 1);
    unsigned l0  = __shfl(a0.u[0], b),      l1  = __shfl(a0.u[1], b);
    unsigned l0h = __shfl(a0.u[0], b + 16), l1h = __shfl(a0.u[1], b + 16);
    unsigned h0  = __shfl(a1.u[0], b),      h1  = __shfl(a1.u[1], b);
    unsigned h0h = __shfl(a1.u[0], b + 16), h1h = __shfl(a1.u[1], b + 16);
    bool hi = (gi & 2);
    union { bf16x8 v8; unsigned u[4]; } r;
    r.u[0] = hi ? h0 : l0;   r.u[1] = hi ? h1 : l1;
    r.u[2] = hi ? h0h : l0h; r.u[3] = hi ? h1h : l1h;
    return r.v8;
}
#endif

// ---------------- fused main kernel: one window per block, one head per wave ----------------
// q,k,v,S,P all live in registers; LDS only for x/attn-out + f32 out staging.
__global__ __launch_bounds__(384, 3)
void wattn_main(const float* __restrict__ x, const bf16* __restrict__ wqkvT,
                const float* __restrict__ bq, const float* __restrict__ bkv,
                const bf16* __restrict__ projT, const float* __restrict__ biasB,
                const float* __restrict__ proj_b, float* __restrict__ outg)
{
    __shared__ __align__(16) bf16 smem[SMEM_ELEMS];
    const int tid = threadIdx.x;
    const int li  = tid & 15;
    const int gi  = (tid >> 4) & 3;
    const int w   = tid >> 6;        // wave = head, 0..5
    const int win = blockIdx.x;

    bf16* xb = smem;
    const int srow = tid / 48, scol = tid % 48;
    const f32x4 fz = {0.f, 0.f, 0.f, 0.f};

    // ---- stage x: f32 global -> bf16 LDS [64][208] ----
    {
        const float4* xg = (const float4*)(x + (size_t)win * 12288);
#pragma unroll
        for (int i = 0; i < 8; ++i) {
            float4 p = xg[(srow + 8 * i) * 48 + scol];
            bf16x4 v; v[0]=(bf16)p.x; v[1]=(bf16)p.y; v[2]=(bf16)p.z; v[3]=(bf16)p.w;
            *(bf16x4*)&xb[(srow + 8 * i) * XSTR + scol * 4] = v;
        }
    }
    __syncthreads();                                     // B1

    // ======== pass A: q,k via TRANSPOSED GEMM (D: rows=features, cols=tokens) ========
    bf16x4 qf[2][4], kf[2][4];
    {
        f32x4 aqk[4][4];
#pragma unroll
        for (int j = 0; j < 4; ++j)
#pragma unroll
            for (int c = 0; c < 4; ++c) aqk[j][c] = fz;
#pragma unroll 1
        for (int kk = 0; kk < 6; ++kk) {
            bf16x8 bx[4], aw[4];
#pragma unroll
            for (int c = 0; c < 4; ++c)
                bx[c] = *(const bf16x8*)&xb[(c * 16 + li) * XSTR + kk * 32 + gi * 8];
#pragma unroll
            for (int j = 0; j < 4; ++j) {
                int T = (j < 2) ? (2 * w + j) : (12 + 2 * w + (j - 2));
                aw[j] = *(const bf16x8*)&wqkvT[(size_t)(T * 16 + li) * 192 + kk * 32 + gi * 8];
            }
#pragma unroll
            for (int j = 0; j < 4; ++j)
#pragma unroll
                for (int c = 0; c < 4; ++c)
                    aqk[j][c] = __builtin_amdgcn_mfma_f32_16x16x32_bf16(aw[j], bx[c], aqk[j][c], 0, 0, 0);
        }
        // epilogue A -> registers (lane: feature = 32w+16j+4gi+rg, token = 16c+li)
#pragma unroll
        for (int j = 0; j < 2; ++j) {
            f32x4 bjq = *(const f32x4*)&bq [32 * w + 16 * j + 4 * gi];
            f32x4 bjk = *(const f32x4*)&bkv[32 * w + 16 * j + 4 * gi];
#pragma unroll
            for (int c = 0; c < 4; ++c) {
                bf16x4 rq, rk;
#pragma unroll
                for (int rg = 0; rg < 4; ++rg) {
                    float tq = aqk[j][c][rg]     + bjq[rg];
                    float tk = aqk[2 + j][c][rg] + bjk[rg];
                    tq = (fmaxf(tq, 0.f) + 0.2f * fminf(tq, 0.f)) * SCALE;
                    tk =  fmaxf(tk, 0.f) + 0.2f * fminf(tk, 0.f);
                    rq[rg] = (bf16)tq;
                    rk[rg] = (bf16)tk;
                }
                qf[j][c] = rq;
                kf[j][c] = rk;
            }
        }
    }

    // ======== pass B: v via NORMAL GEMM (D: rows=tokens, cols=features) ========
    // D-layout of v == A-fragment of v^T for the K=16 MFMA -> v never touches LDS.
    bf16x4 vf[2][4];   // [ct = d-half][rt = m-subtile]
    {
        f32x4 av_[4][2];
#pragma unroll
        for (int rt = 0; rt < 4; ++rt)
#pragma unroll
            for (int j = 0; j < 2; ++j) av_[rt][j] = fz;
#pragma unroll 1
        for (int kk = 0; kk < 6; ++kk) {
            bf16x8 a[4], bwv[2];
#pragma unroll
            for (int rt = 0; rt < 4; ++rt)
                a[rt] = *(const bf16x8*)&xb[(rt * 16 + li) * XSTR + kk * 32 + gi * 8];
#pragma unroll
            for (int j = 0; j < 2; ++j)
                bwv[j] = *(const bf16x8*)&wqkvT[(size_t)((24 + 2 * w + j) * 16 + li) * 192 + kk * 32 + gi * 8];
#pragma unroll
            for (int rt = 0; rt < 4; ++rt)
#pragma unroll
                for (int j = 0; j < 2; ++j)
                    av_[rt][j] = __builtin_amdgcn_mfma_f32_16x16x32_bf16(a[rt], bwv[j], av_[rt][j], 0, 0, 0);
        }
        __syncthreads();                                 // B2 (all xb reads done)
#pragma unroll
        for (int j = 0; j < 2; ++j) {
            f32x4 bjv = *(const f32x4*)&bkv[192 + 32 * w + 16 * j + 4 * gi];
#pragma unroll
            for (int rt = 0; rt < 4; ++rt) {
                bf16x4 r;
#pragma unroll
                for (int rg = 0; rg < 4; ++rg) {
                    float t = av_[rt][j][rg] + bjv[rg];
                    t = fmaxf(t, 0.f) + 0.2f * fminf(t, 0.f);
                    r[rg] = (bf16)t;
                }
                vf[j][rt] = r;
            }
        }
    }

    // ======== QK^T from registers: S^T tiles s[cm][cn] ========
    f32x4 s[4][4];
#if defined(HAS_MFMA16)
#pragma unroll
    for (int cm = 0; cm < 4; ++cm)
#pragma unroll
        for (int cn = 0; cn < 4; ++cn) {
            f32x4 t = __builtin_amdgcn_mfma_f32_16x16x16bf16_1k(
                __builtin_bit_cast(s16x4, kf[0][cm]), __builtin_bit_cast(s16x4, qf[0][cn]), fz, 0, 0, 0);
            s[cm][cn] = __builtin_amdgcn_mfma_f32_16x16x16bf16_1k(
                __builtin_bit_cast(s16x4, kf[1][cm]), __builtin_bit_cast(s16x4, qf[1][cn]), t, 0, 0, 0);
        }
#else
    {
        bf16x8 ka[4], qb[4];
#pragma unroll
        for (int cm = 0; cm < 4; ++cm) ka[cm] = build8(kf[0][cm], kf[1][cm], li, gi);
#pragma unroll
        for (int cn = 0; cn < 4; ++cn) qb[cn] = build8(qf[0][cn], qf[1][cn], li, gi);
#pragma unroll
        for (int cm = 0; cm < 4; ++cm)
#pragma unroll
            for (int cn = 0; cn < 4; ++cn)
                s[cm][cn] = __builtin_amdgcn_mfma_f32_16x16x32_bf16(ka[cm], qb[cn], fz, 0, 0, 0);
    }
#endif

    // ======== + bias, softmax over keys, P -> bf16 regs ========
    float rs[4];
    bf16x4 pb[4][4];
#pragma unroll
    for (int cn = 0; cn < 4; ++cn) {
        float m_ = -1e30f;
#pragma unroll
        for (int cm = 0; cm < 4; ++cm) {
            s[cm][cn] += *(const f32x4*)&biasB[w * 4096 + (4 * cm + gi) * 256 + (16 * cn + li) * 4];
#pragma unroll
            for (int rg = 0; rg < 4; ++rg) m_ = fmaxf(m_, s[cm][cn][rg]);
        }
        m_ = fmaxf(m_, __shfl_xor(m_, 16));
        m_ = fmaxf(m_, __shfl_xor(m_, 32));
        float ss = 0.f;
#pragma unroll
        for (int cm = 0; cm < 4; ++cm) {
            bf16x4 r;
#pragma unroll
            for (int rg = 0; rg < 4; ++rg) {
                float p = __expf(s[cm][cn][rg] - m_);
                ss += p;
                r[rg] = (bf16)p;
            }
            pb[cm][cn] = r;
        }
        ss += __shfl_xor(ss, 16);
        ss += __shfl_xor(ss, 32);
        rs[cn] = 1.f / ss;
    }

    // ======== PV entirely from registers: out^T tiles o[ct][cn] ========
    f32x4 o[2][4];
#pragma unroll
    for (int ct = 0; ct < 2; ++ct)
#pragma unroll
        for (int cn = 0; cn < 4; ++cn) {
#if defined(HAS_MFMA16)
            f32x4 t = fz;
#pragma unroll
            for (int rt = 0; rt < 4; ++rt)
                t = __builtin_amdgcn_mfma_f32_16x16x16bf16_1k(
                        __builtin_bit_cast(s16x4, vf[ct][rt]),
                        __builtin_bit_cast(s16x4, pb[rt][cn]), t, 0, 0, 0);
            o[ct][cn] = t;
#else
            f32x4 t = fz;
#pragma unroll
            for (int c = 0; c < 2; ++c)
                t = __builtin_amdgcn_mfma_f32_16x16x32_bf16(
                        build8(vf[ct][2 * c], vf[ct][2 * c + 1], li, gi),
                        build8(pb[2 * c][cn], pb[2 * c + 1][cn], li, gi), t, 0, 0, 0);
            o[ct][cn] = t;
#endif
        }
    // normalize + write attn-out [n][c] into xb (x dead since B2)
#pragma unroll
    for (int ct = 0; ct < 2; ++ct)
#pragma unroll
        for (int cn = 0; cn < 4; ++cn) {
            bf16x4 r;
#pragma unroll
            for (int rg = 0; rg < 4; ++rg) r[rg] = (bf16)(o[ct][cn][rg] * rs[cn]);
            *(bf16x4*)&xb[(cn * 16 + li) * XSTR + 32 * w + 16 * ct + 4 * gi] = r;
        }
    __syncthreads();                                     // B3 (attn-out complete)

    // ======== proj (transposed): pa[ct][cn]; A=projT rows, B=attn-out cols ========
    f32x4 pa[2][4];
#pragma unroll
    for (int ct = 0; ct < 2; ++ct)
#pragma unroll
        for (int cn = 0; cn < 4; ++cn) pa[ct][cn] = fz;
#pragma unroll 1
    for (int kk = 0; kk < 6; ++kk) {
        bf16x8 bo[4], awp[2];
#pragma unroll
        for (int cn = 0; cn < 4; ++cn)
            bo[cn] = *(const bf16x8*)&xb[(cn * 16 + li) * XSTR + kk * 32 + gi * 8];
#pragma unroll
        for (int ct = 0; ct < 2; ++ct)
            awp[ct] = *(const bf16x8*)&projT[(size_t)((2 * w + ct) * 16 + li) * 192 + kk * 32 + gi * 8];
#pragma unroll
        for (int ct = 0; ct < 2; ++ct)
#pragma unroll
            for (int cn = 0; cn < 4; ++cn)
                pa[ct][cn] = __builtin_amdgcn_mfma_f32_16x16x32_bf16(awp[ct], bo[cn], pa[ct][cn], 0, 0, 0);
    }

    // ---- + proj bias -> f32 stage [64][196] (separate LDS region; no barrier before) ----
    {
        float* of = (float*)(smem + OFF_F);
#pragma unroll
        for (int ct = 0; ct < 2; ++ct) {
            f32x4 pbv = *(const f32x4*)&proj_b[32 * w + 16 * ct + 4 * gi];
#pragma unroll
            for (int cn = 0; cn < 4; ++cn) {
                f32x4 y = pa[ct][cn];
#pragma unroll
                for (int rg = 0; rg < 4; ++rg) y[rg] += pbv[rg];
                *(f32x4*)&of[(cn * 16 + li) * FSTR + 32 * w + 16 * ct + 4 * gi] = y;
            }
        }
    }
    __syncthreads();                                     // B4

    // ---- coalesced copy-out ----
    {
        const float* of = (const float*)(smem + OFF_F);
        float4* og = (float4*)(outg + (size_t)win * 12288);
#pragma unroll
        for (int i = 0; i < 8; ++i)
            og[(srow + 8 * i) * 48 + scol] = *(const float4*)&of[(srow + 8 * i) * FSTR + scol * 4];
    }
}

extern "C" void kernel_launch(void* const* d_in, const int* in_sizes, int n_in,
                              void* d_out, int out_size, void* d_ws, size_t ws_size,
                              hipStream_t stream)
{
    const float* x          = (const float*)d_in[0];
    const float* wq         = (const float*)d_in[1];
    const float* bq         = (const float*)d_in[2];
    const float* wkv        = (const float*)d_in[3];
    const float* bkv        = (const float*)d_in[4];
    const float* bias_table = (const float*)d_in[5];
    const float* proj_w     = (const float*)d_in[6];
    const float* proj_b     = (const float*)d_in[7];
    float* out = (float*)d_out;

    int B = in_sizes[0] / (64 * 192);

    bf16*  wqkvT = (bf16*)d_ws;
    bf16*  projT = (bf16*)((char*)d_ws + 221184);
    float* biasB = (float*)((char*)d_ws + 294912);

    wattn_prep<<<672, 256, 0, stream>>>(wq, wkv, bias_table, proj_w, wqkvT, projT, biasB);

    wattn_main<<<B, 384, 0, stream>>>(x, wqkvT, bq, bkv, projT, biasB, proj_b, out);
}

// Round 6
// 265.142 us; speedup vs baseline: 1.4913x; 1.0060x over previous
//
#include <hip/hip_runtime.h>
#include <hip/hip_bf16.h>

typedef __bf16 bf16;
typedef bf16 bf16x8 __attribute__((ext_vector_type(8)));
typedef bf16 bf16x4 __attribute__((ext_vector_type(4)));
typedef short s16x4 __attribute__((ext_vector_type(4)));
typedef float f32x4 __attribute__((ext_vector_type(4)));

#define SCALE 0.17677669529663687f  // 1/sqrt(32)

// LDS: xb bf16 [64][208] @0 (26,624B, x -> attn-out) ;
//      f32 out-stage [64][196] @13312 elems (50,176B). total 76,800B.
// Reg budget <=128/wave (launch_bounds(384,4)) -> 4 waves/SIMD quantum
// -> 16-wave/CU capacity -> 2 six-wave blocks resident.
#define XSTR 208
#define FSTR 196
#define OFF_F 13312                 // bf16 units
#define SMEM_ELEMS 38400

#if defined(__has_builtin)
#if __has_builtin(__builtin_amdgcn_mfma_f32_16x16x16bf16_1k)
#define HAS_MFMA16 1
#endif
#endif

// ---------------- prep kernel (unchanged, validated) ----------------
__global__ void wattn_prep(const float* __restrict__ wq, const float* __restrict__ wkv,
                           const float* __restrict__ bias_table, const float* __restrict__ proj_w,
                           bf16* __restrict__ wqkvT, bf16* __restrict__ projT,
                           float* __restrict__ biasB)
{
    int t = blockIdx.x * 256 + threadIdx.x;
    if (t < 110592) {                       // wqkvT[n][k] = W[k][n]
        int n = t / 192, k = t % 192;
        float v = (n < 192) ? wq[k * 192 + n] : wkv[k * 384 + (n - 192)];
        wqkvT[t] = (bf16)v;
    } else if (t < 147456) {                // projT[n][k] = proj_w[k][n]
        int e = t - 110592;
        int n = e / 192, k = e % 192;
        projT[e] = (bf16)proj_w[k * 192 + n];
    } else if (t < 172032) {                // biasB[h][m>>2][n][m&3]
        int e = t - 147456;
        int h  = e >> 12;
        int mb = (e >> 8) & 15;
        int n  = (e >> 2) & 63;
        int mr = e & 3;
        int m  = mb * 4 + mr;
        int idx = ((n & 7) - (m & 7) + 7) * 15 + ((n >> 3) - (m >> 3) + 7);
        biasB[e] = bias_table[idx * 6 + h];
    }
}

#if !defined(HAS_MFMA16)
// fallback: build K=32 frag from two D-layout bf16x4 tiles via shuffles
__device__ __forceinline__ bf16x8 build8(bf16x4 t0, bf16x4 t1, int li, int gi) {
    union { bf16x4 v; unsigned u[2]; } a0, a1;
    a0.v = t0; a1.v = t1;
    int b = li + 32 * (gi & 1);
    unsigned l0  = __shfl(a0.u[0], b),      l1  = __shfl(a0.u[1], b);
    unsigned l0h = __shfl(a0.u[0], b + 16), l1h = __shfl(a0.u[1], b + 16);
    unsigned h0  = __shfl(a1.u[0], b),      h1  = __shfl(a1.u[1], b);
    unsigned h0h = __shfl(a1.u[0], b + 16), h1h = __shfl(a1.u[1], b + 16);
    bool hi = (gi & 2);
    union { bf16x8 v8; unsigned u[4]; } r;
    r.u[0] = hi ? h0 : l0;   r.u[1] = hi ? h1 : l1;
    r.u[2] = hi ? h0h : l0h; r.u[3] = hi ? h1h : l1h;
    return r.v8;
}
#endif

// ---------------- fused main kernel: one window per block, one head per wave ----------------
// Phase order chosen so no two large register states coexist (<=128 regs):
// stage -> B1 -> passA(q,k) -> QK^T -> softmax(P) -> passB(v) -> PV -> B2 ->
// attn-out -> B3 -> proj -> f32 stage -> B4 -> copyout
__global__ __launch_bounds__(384, 4)
void wattn_main(const float* __restrict__ x, const bf16* __restrict__ wqkvT,
                const float* __restrict__ bq, const float* __restrict__ bkv,
                const bf16* __restrict__ projT, const float* __restrict__ biasB,
                const float* __restrict__ proj_b, float* __restrict__ outg)
{
    __shared__ __align__(16) bf16 smem[SMEM_ELEMS];
    const int tid = threadIdx.x;
    const int li  = tid & 15;
    const int gi  = (tid >> 4) & 3;
    const int w   = tid >> 6;        // wave = head, 0..5
    const int win = blockIdx.x;

    bf16* xb = smem;
    const int srow = tid / 48, scol = tid % 48;
    const f32x4 fz = {0.f, 0.f, 0.f, 0.f};

    // ---- stage x: f32 global -> bf16 LDS [64][208] ----
    {
        const float4* xg = (const float4*)(x + (size_t)win * 12288);
#pragma unroll
        for (int i = 0; i < 8; ++i) {
            float4 p = xg[(srow + 8 * i) * 48 + scol];
            bf16x4 v; v[0]=(bf16)p.x; v[1]=(bf16)p.y; v[2]=(bf16)p.z; v[3]=(bf16)p.w;
            *(bf16x4*)&xb[(srow + 8 * i) * XSTR + scol * 4] = v;
        }
    }
    __syncthreads();                                     // B1

    // ======== pass A: q,k via TRANSPOSED GEMM (D: rows=features, cols=tokens) ========
    bf16x4 qf[2][4], kf[2][4];
    {
        f32x4 aqk[4][4];
#pragma unroll
        for (int j = 0; j < 4; ++j)
#pragma unroll
            for (int c = 0; c < 4; ++c) aqk[j][c] = fz;
#pragma unroll 2
        for (int kk = 0; kk < 6; ++kk) {
            bf16x8 bx[4], aw[4];
#pragma unroll
            for (int c = 0; c < 4; ++c)
                bx[c] = *(const bf16x8*)&xb[(c * 16 + li) * XSTR + kk * 32 + gi * 8];
#pragma unroll
            for (int j = 0; j < 4; ++j) {
                int T = (j < 2) ? (2 * w + j) : (12 + 2 * w + (j - 2));
                aw[j] = *(const bf16x8*)&wqkvT[(size_t)(T * 16 + li) * 192 + kk * 32 + gi * 8];
            }
#pragma unroll
            for (int j = 0; j < 4; ++j)
#pragma unroll
                for (int c = 0; c < 4; ++c)
                    aqk[j][c] = __builtin_amdgcn_mfma_f32_16x16x32_bf16(aw[j], bx[c], aqk[j][c], 0, 0, 0);
        }
        // epilogue A -> registers (lane: feature = 32w+16j+4gi+rg, token = 16c+li)
#pragma unroll
        for (int j = 0; j < 2; ++j) {
            f32x4 bjq = *(const f32x4*)&bq [32 * w + 16 * j + 4 * gi];
            f32x4 bjk = *(const f32x4*)&bkv[32 * w + 16 * j + 4 * gi];
#pragma unroll
            for (int c = 0; c < 4; ++c) {
                bf16x4 rq, rk;
#pragma unroll
                for (int rg = 0; rg < 4; ++rg) {
                    float tq = aqk[j][c][rg]     + bjq[rg];
                    float tk = aqk[2 + j][c][rg] + bjk[rg];
                    tq = (fmaxf(tq, 0.f) + 0.2f * fminf(tq, 0.f)) * SCALE;
                    tk =  fmaxf(tk, 0.f) + 0.2f * fminf(tk, 0.f);
                    rq[rg] = (bf16)tq;
                    rk[rg] = (bf16)tk;
                }
                qf[j][c] = rq;
                kf[j][c] = rk;
            }
        }
    }

    // ======== QK^T from registers: S^T tiles s[cm][cn]; qf/kf die here ========
    f32x4 s[4][4];
#if defined(HAS_MFMA16)
#pragma unroll
    for (int cm = 0; cm < 4; ++cm)
#pragma unroll
        for (int cn = 0; cn < 4; ++cn) {
            f32x4 t = __builtin_amdgcn_mfma_f32_16x16x16bf16_1k(
                __builtin_bit_cast(s16x4, kf[0][cm]), __builtin_bit_cast(s16x4, qf[0][cn]), fz, 0, 0, 0);
            s[cm][cn] = __builtin_amdgcn_mfma_f32_16x16x16bf16_1k(
                __builtin_bit_cast(s16x4, kf[1][cm]), __builtin_bit_cast(s16x4, qf[1][cn]), t, 0, 0, 0);
        }
#else
    {
        bf16x8 ka[4], qb[4];
#pragma unroll
        for (int cm = 0; cm < 4; ++cm) ka[cm] = build8(kf[0][cm], kf[1][cm], li, gi);
#pragma unroll
        for (int cn = 0; cn < 4; ++cn) qb[cn] = build8(qf[0][cn], qf[1][cn], li, gi);
#pragma unroll
        for (int cm = 0; cm < 4; ++cm)
#pragma unroll
            for (int cn = 0; cn < 4; ++cn)
                s[cm][cn] = __builtin_amdgcn_mfma_f32_16x16x32_bf16(ka[cm], qb[cn], fz, 0, 0, 0);
    }
#endif

    // ======== + bias, softmax over keys; s dies into pb ========
    float rs[4];
    bf16x4 pb[4][4];
#pragma unroll
    for (int cn = 0; cn < 4; ++cn) {
        float m_ = -1e30f;
#pragma unroll
        for (int cm = 0; cm < 4; ++cm) {
            s[cm][cn] += *(const f32x4*)&biasB[w * 4096 + (4 * cm + gi) * 256 + (16 * cn + li) * 4];
#pragma unroll
            for (int rg = 0; rg < 4; ++rg) m_ = fmaxf(m_, s[cm][cn][rg]);
        }
        m_ = fmaxf(m_, __shfl_xor(m_, 16));
        m_ = fmaxf(m_, __shfl_xor(m_, 32));
        float ss = 0.f;
#pragma unroll
        for (int cm = 0; cm < 4; ++cm) {
            bf16x4 r;
#pragma unroll
            for (int rg = 0; rg < 4; ++rg) {
                float p = __expf(s[cm][cn][rg] - m_);
                ss += p;
                r[rg] = (bf16)p;
            }
            pb[cm][cn] = r;
        }
        ss += __shfl_xor(ss, 16);
        ss += __shfl_xor(ss, 32);
        rs[cn] = 1.f / ss;
    }

    // ======== pass B: v via NORMAL GEMM (D rows=tokens, cols=features) ========
    // D-layout of v == A-fragment of v^T for the K=16 MFMA -> v never touches LDS.
    bf16x4 vf[2][4];   // [d-half][m-subtile]
    {
        f32x4 av_[4][2];
#pragma unroll
        for (int rt = 0; rt < 4; ++rt)
#pragma unroll
            for (int j = 0; j < 2; ++j) av_[rt][j] = fz;
#pragma unroll 2
        for (int kk = 0; kk < 6; ++kk) {
            bf16x8 a[4], bwv[2];
#pragma unroll
            for (int rt = 0; rt < 4; ++rt)
                a[rt] = *(const bf16x8*)&xb[(rt * 16 + li) * XSTR + kk * 32 + gi * 8];
#pragma unroll
            for (int j = 0; j < 2; ++j)
                bwv[j] = *(const bf16x8*)&wqkvT[(size_t)((24 + 2 * w + j) * 16 + li) * 192 + kk * 32 + gi * 8];
#pragma unroll
            for (int rt = 0; rt < 4; ++rt)
#pragma unroll
                for (int j = 0; j < 2; ++j)
                    av_[rt][j] = __builtin_amdgcn_mfma_f32_16x16x32_bf16(a[rt], bwv[j], av_[rt][j], 0, 0, 0);
        }
#pragma unroll
        for (int j = 0; j < 2; ++j) {
            f32x4 bjv = *(const f32x4*)&bkv[192 + 32 * w + 16 * j + 4 * gi];
#pragma unroll
            for (int rt = 0; rt < 4; ++rt) {
                bf16x4 r;
#pragma unroll
                for (int rg = 0; rg < 4; ++rg) {
                    float t = av_[rt][j][rg] + bjv[rg];
                    t = fmaxf(t, 0.f) + 0.2f * fminf(t, 0.f);
                    r[rg] = (bf16)t;
                }
                vf[j][rt] = r;
            }
        }
    }

    // ======== PV entirely from registers: out^T tiles o[ct][cn] ========
    f32x4 o[2][4];
#pragma unroll
    for (int ct = 0; ct < 2; ++ct)
#pragma unroll
        for (int cn = 0; cn < 4; ++cn) {
#if defined(HAS_MFMA16)
            f32x4 t = fz;
#pragma unroll
            for (int rt = 0; rt < 4; ++rt)
                t = __builtin_amdgcn_mfma_f32_16x16x16bf16_1k(
                        __builtin_bit_cast(s16x4, vf[ct][rt]),
                        __builtin_bit_cast(s16x4, pb[rt][cn]), t, 0, 0, 0);
            o[ct][cn] = t;
#else
            f32x4 t = fz;
#pragma unroll
            for (int c = 0; c < 2; ++c)
                t = __builtin_amdgcn_mfma_f32_16x16x32_bf16(
                        build8(vf[ct][2 * c], vf[ct][2 * c + 1], li, gi),
                        build8(pb[2 * c][cn], pb[2 * c + 1][cn], li, gi), t, 0, 0, 0);
            o[ct][cn] = t;
#endif
        }
    __syncthreads();                                     // B2 (all xb reads done)

    // normalize + write attn-out [n][c] into xb
#pragma unroll
    for (int ct = 0; ct < 2; ++ct)
#pragma unroll
        for (int cn = 0; cn < 4; ++cn) {
            bf16x4 r;
#pragma unroll
            for (int rg = 0; rg < 4; ++rg) r[rg] = (bf16)(o[ct][cn][rg] * rs[cn]);
            *(bf16x4*)&xb[(cn * 16 + li) * XSTR + 32 * w + 16 * ct + 4 * gi] = r;
        }
    __syncthreads();                                     // B3 (attn-out complete)

    // ======== proj (transposed): pa[ct][cn]; A=projT rows, B=attn-out cols ========
    f32x4 pa[2][4];
#pragma unroll
    for (int ct = 0; ct < 2; ++ct)
#pragma unroll
        for (int cn = 0; cn < 4; ++cn) pa[ct][cn] = fz;
#pragma unroll 2
    for (int kk = 0; kk < 6; ++kk) {
        bf16x8 bo[4], awp[2];
#pragma unroll
        for (int cn = 0; cn < 4; ++cn)
            bo[cn] = *(const bf16x8*)&xb[(cn * 16 + li) * XSTR + kk * 32 + gi * 8];
#pragma unroll
        for (int ct = 0; ct < 2; ++ct)
            awp[ct] = *(const bf16x8*)&projT[(size_t)((2 * w + ct) * 16 + li) * 192 + kk * 32 + gi * 8];
#pragma unroll
        for (int ct = 0; ct < 2; ++ct)
#pragma unroll
            for (int cn = 0; cn < 4; ++cn)
                pa[ct][cn] = __builtin_amdgcn_mfma_f32_16x16x32_bf16(awp[ct], bo[cn], pa[ct][cn], 0, 0, 0);
    }

    // ---- + proj bias -> f32 stage [64][196] (separate LDS region) ----
    {
        float* of = (float*)(smem + OFF_F);
#pragma unroll
        for (int ct = 0; ct < 2; ++ct) {
            f32x4 pbv = *(const f32x4*)&proj_b[32 * w + 16 * ct + 4 * gi];
#pragma unroll
            for (int cn = 0; cn < 4; ++cn) {
                f32x4 y = pa[ct][cn];
#pragma unroll
                for (int rg = 0; rg < 4; ++rg) y[rg] += pbv[rg];
                *(f32x4*)&of[(cn * 16 + li) * FSTR + 32 * w + 16 * ct + 4 * gi] = y;
            }
        }
    }
    __syncthreads();                                     // B4

    // ---- coalesced copy-out ----
    {
        const float* of = (const float*)(smem + OFF_F);
        float4* og = (float4*)(outg + (size_t)win * 12288);
#pragma unroll
        for (int i = 0; i < 8; ++i)
            og[(srow + 8 * i) * 48 + scol] = *(const float4*)&of[(srow + 8 * i) * FSTR + scol * 4];
    }
}

extern "C" void kernel_launch(void* const* d_in, const int* in_sizes, int n_in,
                              void* d_out, int out_size, void* d_ws, size_t ws_size,
                              hipStream_t stream)
{
    const float* x          = (const float*)d_in[0];
    const float* wq         = (const float*)d_in[1];
    const float* bq         = (const float*)d_in[2];
    const float* wkv        = (const float*)d_in[3];
    const float* bkv        = (const float*)d_in[4];
    const float* bias_table = (const float*)d_in[5];
    const float* proj_w     = (const float*)d_in[6];
    const float* proj_b     = (const float*)d_in[7];
    float* out = (float*)d_out;

    int B = in_sizes[0] / (64 * 192);

    bf16*  wqkvT = (bf16*)d_ws;
    bf16*  projT = (bf16*)((char*)d_ws + 221184);
    float* biasB = (float*)((char*)d_ws + 294912);

    wattn_prep<<<672, 256, 0, stream>>>(wq, wkv, bias_table, proj_w, wqkvT, projT, biasB);

    wattn_main<<<B, 384, 0, stream>>>(x, wqkvT, bq, bkv, projT, biasB, proj_b, out);
}

// Round 7
// 258.838 us; speedup vs baseline: 1.5276x; 1.0244x over previous
//
#include <hip/hip_runtime.h>
#include <hip/hip_bf16.h>

typedef __bf16 bf16;
typedef bf16 bf16x8 __attribute__((ext_vector_type(8)));
typedef bf16 bf16x4 __attribute__((ext_vector_type(4)));
typedef short s16x4 __attribute__((ext_vector_type(4)));
typedef float f32x4 __attribute__((ext_vector_type(4)));

#define SCALE 0.17677669529663687f  // 1/sqrt(32)

// Two windows per 768-thread block (12 waves = 3/SIMD, balanced).
// Per window: xb bf16 [64][208] (26,624B) ; f32 out-stage [64][196] (25,088 f32).
// Total LDS = 2*13312 + 2*25088(bf16 units) = 76,800 elems = 153,600 B -> 1 block/CU.
#define XSTR 208
#define FSTR 196
#define XELEMS 13312                // per-window xb elems
#define OFF_F 26624                 // bf16-unit offset of f32 stage area
#define FELEMS 25088                // per-window stage, in bf16 units (12,544 f32)
#define SMEM_ELEMS 76800

#if defined(__has_builtin)
#if __has_builtin(__builtin_amdgcn_mfma_f32_16x16x16bf16_1k)
#define HAS_MFMA16 1
#endif
#endif

// ---------------- prep kernel (unchanged, validated) ----------------
__global__ void wattn_prep(const float* __restrict__ wq, const float* __restrict__ wkv,
                           const float* __restrict__ bias_table, const float* __restrict__ proj_w,
                           bf16* __restrict__ wqkvT, bf16* __restrict__ projT,
                           float* __restrict__ biasB)
{
    int t = blockIdx.x * 256 + threadIdx.x;
    if (t < 110592) {                       // wqkvT[n][k] = W[k][n]
        int n = t / 192, k = t % 192;
        float v = (n < 192) ? wq[k * 192 + n] : wkv[k * 384 + (n - 192)];
        wqkvT[t] = (bf16)v;
    } else if (t < 147456) {                // projT[n][k] = proj_w[k][n]
        int e = t - 110592;
        int n = e / 192, k = e % 192;
        projT[e] = (bf16)proj_w[k * 192 + n];
    } else if (t < 172032) {                // biasB[h][m>>2][n][m&3]
        int e = t - 147456;
        int h  = e >> 12;
        int mb = (e >> 8) & 15;
        int n  = (e >> 2) & 63;
        int mr = e & 3;
        int m  = mb * 4 + mr;
        int idx = ((n & 7) - (m & 7) + 7) * 15 + ((n >> 3) - (m >> 3) + 7);
        biasB[e] = bias_table[idx * 6 + h];
    }
}

#if !defined(HAS_MFMA16)
// fallback: build K=32 frag from two D-layout bf16x4 tiles via shuffles
__device__ __forceinline__ bf16x8 build8(bf16x4 t0, bf16x4 t1, int li, int gi) {
    union { bf16x4 v; unsigned u[2]; } a0, a1;
    a0.v = t0; a1.v = t1;
    int b = li + 32 * (gi & 1);
    unsigned l0  = __shfl(a0.u[0], b),      l1  = __shfl(a0.u[1], b);
    unsigned l0h = __shfl(a0.u[0], b + 16), l1h = __shfl(a0.u[1], b + 16);
    unsigned h0  = __shfl(a1.u[0], b),      h1  = __shfl(a1.u[1], b);
    unsigned h0h = __shfl(a1.u[0], b + 16), h1h = __shfl(a1.u[1], b + 16);
    bool hi = (gi & 2);
    union { bf16x8 v8; unsigned u[4]; } r;
    r.u[0] = hi ? h0 : l0;   r.u[1] = hi ? h1 : l1;
    r.u[2] = hi ? h0h : l0h; r.u[3] = hi ? h1h : l1h;
    return r.v8;
}
#endif

// ---------------- fused main kernel: TWO windows per block, one head per wave ----------------
// waves 0-5 -> window A (wave = head), waves 6-11 -> window B.
// Per window: stage -> B1 -> passA(q,k) -> QK^T -> softmax -> passB(v) -> PV -> B2 ->
// attn-out -> B3 -> proj -> f32 stage -> B4 -> copyout
__global__ __launch_bounds__(768, 3)
void wattn_main(const float* __restrict__ x, const bf16* __restrict__ wqkvT,
                const float* __restrict__ bq, const float* __restrict__ bkv,
                const bf16* __restrict__ projT, const float* __restrict__ biasB,
                const float* __restrict__ proj_b, float* __restrict__ outg, int Btot)
{
    __shared__ __align__(16) bf16 smem[SMEM_ELEMS];
    const int tid = threadIdx.x;
    const int li  = tid & 15;
    const int gi  = (tid >> 4) & 3;
    const int ww  = tid >> 6;          // wave 0..11
    const int W   = (ww >= 6);         // window half 0/1
    const int w   = ww - 6 * W;        // head 0..5

    const int winRaw = blockIdx.x * 2 + W;
    const bool valid = (winRaw < Btot);
    const int win = valid ? winRaw : (Btot - 1);

    bf16* xb = smem + W * XELEMS;
    float* of = (float*)(smem + OFF_F + W * FELEMS);

    const int t384 = tid - 384 * W;    // 0..383 within window
    const int srow = t384 / 48, scol = t384 % 48;
    const f32x4 fz = {0.f, 0.f, 0.f, 0.f};

    // ---- stage x: f32 global -> bf16 LDS [64][208] ----
    {
        const float4* xg = (const float4*)(x + (size_t)win * 12288);
#pragma unroll
        for (int i = 0; i < 8; ++i) {
            float4 p = xg[(srow + 8 * i) * 48 + scol];
            bf16x4 v; v[0]=(bf16)p.x; v[1]=(bf16)p.y; v[2]=(bf16)p.z; v[3]=(bf16)p.w;
            *(bf16x4*)&xb[(srow + 8 * i) * XSTR + scol * 4] = v;
        }
    }
    __syncthreads();                                     // B1

    // ======== pass A: q,k via TRANSPOSED GEMM (D: rows=features, cols=tokens) ========
    bf16x4 qf[2][4], kf[2][4];
    {
        f32x4 aqk[4][4];
#pragma unroll
        for (int j = 0; j < 4; ++j)
#pragma unroll
            for (int c = 0; c < 4; ++c) aqk[j][c] = fz;
#pragma unroll 2
        for (int kk = 0; kk < 6; ++kk) {
            bf16x8 bx[4], aw[4];
#pragma unroll
            for (int c = 0; c < 4; ++c)
                bx[c] = *(const bf16x8*)&xb[(c * 16 + li) * XSTR + kk * 32 + gi * 8];
#pragma unroll
            for (int j = 0; j < 4; ++j) {
                int T = (j < 2) ? (2 * w + j) : (12 + 2 * w + (j - 2));
                aw[j] = *(const bf16x8*)&wqkvT[(size_t)(T * 16 + li) * 192 + kk * 32 + gi * 8];
            }
#pragma unroll
            for (int j = 0; j < 4; ++j)
#pragma unroll
                for (int c = 0; c < 4; ++c)
                    aqk[j][c] = __builtin_amdgcn_mfma_f32_16x16x32_bf16(aw[j], bx[c], aqk[j][c], 0, 0, 0);
        }
        // epilogue A -> registers (lane: feature = 32w+16j+4gi+rg, token = 16c+li)
#pragma unroll
        for (int j = 0; j < 2; ++j) {
            f32x4 bjq = *(const f32x4*)&bq [32 * w + 16 * j + 4 * gi];
            f32x4 bjk = *(const f32x4*)&bkv[32 * w + 16 * j + 4 * gi];
#pragma unroll
            for (int c = 0; c < 4; ++c) {
                bf16x4 rq, rk;
#pragma unroll
                for (int rg = 0; rg < 4; ++rg) {
                    float tq = aqk[j][c][rg]     + bjq[rg];
                    float tk = aqk[2 + j][c][rg] + bjk[rg];
                    tq = (fmaxf(tq, 0.f) + 0.2f * fminf(tq, 0.f)) * SCALE;
                    tk =  fmaxf(tk, 0.f) + 0.2f * fminf(tk, 0.f);
                    rq[rg] = (bf16)tq;
                    rk[rg] = (bf16)tk;
                }
                qf[j][c] = rq;
                kf[j][c] = rk;
            }
        }
    }

    // ======== QK^T from registers: S^T tiles s[cm][cn]; qf/kf die here ========
    f32x4 s[4][4];
#if defined(HAS_MFMA16)
#pragma unroll
    for (int cm = 0; cm < 4; ++cm)
#pragma unroll
        for (int cn = 0; cn < 4; ++cn) {
            f32x4 t = __builtin_amdgcn_mfma_f32_16x16x16bf16_1k(
                __builtin_bit_cast(s16x4, kf[0][cm]), __builtin_bit_cast(s16x4, qf[0][cn]), fz, 0, 0, 0);
            s[cm][cn] = __builtin_amdgcn_mfma_f32_16x16x16bf16_1k(
                __builtin_bit_cast(s16x4, kf[1][cm]), __builtin_bit_cast(s16x4, qf[1][cn]), t, 0, 0, 0);
        }
#else
    {
        bf16x8 ka[4], qb[4];
#pragma unroll
        for (int cm = 0; cm < 4; ++cm) ka[cm] = build8(kf[0][cm], kf[1][cm], li, gi);
#pragma unroll
        for (int cn = 0; cn < 4; ++cn) qb[cn] = build8(qf[0][cn], qf[1][cn], li, gi);
#pragma unroll
        for (int cm = 0; cm < 4; ++cm)
#pragma unroll
            for (int cn = 0; cn < 4; ++cn)
                s[cm][cn] = __builtin_amdgcn_mfma_f32_16x16x32_bf16(ka[cm], qb[cn], fz, 0, 0, 0);
    }
#endif

    // ======== + bias, softmax over keys; s dies into pb ========
    float rs[4];
    bf16x4 pb[4][4];
#pragma unroll
    for (int cn = 0; cn < 4; ++cn) {
        float m_ = -1e30f;
#pragma unroll
        for (int cm = 0; cm < 4; ++cm) {
            s[cm][cn] += *(const f32x4*)&biasB[w * 4096 + (4 * cm + gi) * 256 + (16 * cn + li) * 4];
#pragma unroll
            for (int rg = 0; rg < 4; ++rg) m_ = fmaxf(m_, s[cm][cn][rg]);
        }
        m_ = fmaxf(m_, __shfl_xor(m_, 16));
        m_ = fmaxf(m_, __shfl_xor(m_, 32));
        float ss = 0.f;
#pragma unroll
        for (int cm = 0; cm < 4; ++cm) {
            bf16x4 r;
#pragma unroll
            for (int rg = 0; rg < 4; ++rg) {
                float p = __expf(s[cm][cn][rg] - m_);
                ss += p;
                r[rg] = (bf16)p;
            }
            pb[cm][cn] = r;
        }
        ss += __shfl_xor(ss, 16);
        ss += __shfl_xor(ss, 32);
        rs[cn] = 1.f / ss;
    }

    // ======== pass B: v via NORMAL GEMM (D rows=tokens, cols=features) ========
    bf16x4 vf[2][4];   // [d-half][m-subtile]
    {
        f32x4 av_[4][2];
#pragma unroll
        for (int rt = 0; rt < 4; ++rt)
#pragma unroll
            for (int j = 0; j < 2; ++j) av_[rt][j] = fz;
#pragma unroll 2
        for (int kk = 0; kk < 6; ++kk) {
            bf16x8 a[4], bwv[2];
#pragma unroll
            for (int rt = 0; rt < 4; ++rt)
                a[rt] = *(const bf16x8*)&xb[(rt * 16 + li) * XSTR + kk * 32 + gi * 8];
#pragma unroll
            for (int j = 0; j < 2; ++j)
                bwv[j] = *(const bf16x8*)&wqkvT[(size_t)((24 + 2 * w + j) * 16 + li) * 192 + kk * 32 + gi * 8];
#pragma unroll
            for (int rt = 0; rt < 4; ++rt)
#pragma unroll
                for (int j = 0; j < 2; ++j)
                    av_[rt][j] = __builtin_amdgcn_mfma_f32_16x16x32_bf16(a[rt], bwv[j], av_[rt][j], 0, 0, 0);
        }
#pragma unroll
        for (int j = 0; j < 2; ++j) {
            f32x4 bjv = *(const f32x4*)&bkv[192 + 32 * w + 16 * j + 4 * gi];
#pragma unroll
            for (int rt = 0; rt < 4; ++rt) {
                bf16x4 r;
#pragma unroll
                for (int rg = 0; rg < 4; ++rg) {
                    float t = av_[rt][j][rg] + bjv[rg];
                    t = fmaxf(t, 0.f) + 0.2f * fminf(t, 0.f);
                    r[rg] = (bf16)t;
                }
                vf[j][rt] = r;
            }
        }
    }

    // ======== PV entirely from registers: out^T tiles o[ct][cn] ========
    f32x4 o[2][4];
#pragma unroll
    for (int ct = 0; ct < 2; ++ct)
#pragma unroll
        for (int cn = 0; cn < 4; ++cn) {
#if defined(HAS_MFMA16)
            f32x4 t = fz;
#pragma unroll
            for (int rt = 0; rt < 4; ++rt)
                t = __builtin_amdgcn_mfma_f32_16x16x16bf16_1k(
                        __builtin_bit_cast(s16x4, vf[ct][rt]),
                        __builtin_bit_cast(s16x4, pb[rt][cn]), t, 0, 0, 0);
            o[ct][cn] = t;
#else
            f32x4 t = fz;
#pragma unroll
            for (int c = 0; c < 2; ++c)
                t = __builtin_amdgcn_mfma_f32_16x16x32_bf16(
                        build8(vf[ct][2 * c], vf[ct][2 * c + 1], li, gi),
                        build8(pb[2 * c][cn], pb[2 * c + 1][cn], li, gi), t, 0, 0, 0);
            o[ct][cn] = t;
#endif
        }
    __syncthreads();                                     // B2 (all xb reads done)

    // normalize + write attn-out [n][c] into xb
#pragma unroll
    for (int ct = 0; ct < 2; ++ct)
#pragma unroll
        for (int cn = 0; cn < 4; ++cn) {
            bf16x4 r;
#pragma unroll
            for (int rg = 0; rg < 4; ++rg) r[rg] = (bf16)(o[ct][cn][rg] * rs[cn]);
            *(bf16x4*)&xb[(cn * 16 + li) * XSTR + 32 * w + 16 * ct + 4 * gi] = r;
        }
    __syncthreads();                                     // B3 (attn-out complete)

    // ======== proj (transposed): pa[ct][cn]; A=projT rows, B=attn-out cols ========
    f32x4 pa[2][4];
#pragma unroll
    for (int ct = 0; ct < 2; ++ct)
#pragma unroll
        for (int cn = 0; cn < 4; ++cn) pa[ct][cn] = fz;
#pragma unroll 2
    for (int kk = 0; kk < 6; ++kk) {
        bf16x8 bo[4], awp[2];
#pragma unroll
        for (int cn = 0; cn < 4; ++cn)
            bo[cn] = *(const bf16x8*)&xb[(cn * 16 + li) * XSTR + kk * 32 + gi * 8];
#pragma unroll
        for (int ct = 0; ct < 2; ++ct)
            awp[ct] = *(const bf16x8*)&projT[(size_t)((2 * w + ct) * 16 + li) * 192 + kk * 32 + gi * 8];
#pragma unroll
        for (int ct = 0; ct < 2; ++ct)
#pragma unroll
            for (int cn = 0; cn < 4; ++cn)
                pa[ct][cn] = __builtin_amdgcn_mfma_f32_16x16x32_bf16(awp[ct], bo[cn], pa[ct][cn], 0, 0, 0);
    }

    // ---- + proj bias -> f32 stage [64][196] (separate LDS region, no barrier needed) ----
#pragma unroll
    for (int ct = 0; ct < 2; ++ct) {
        f32x4 pbv = *(const f32x4*)&proj_b[32 * w + 16 * ct + 4 * gi];
#pragma unroll
        for (int cn = 0; cn < 4; ++cn) {
            f32x4 y = pa[ct][cn];
#pragma unroll
            for (int rg = 0; rg < 4; ++rg) y[rg] += pbv[rg];
            *(f32x4*)&of[(cn * 16 + li) * FSTR + 32 * w + 16 * ct + 4 * gi] = y;
        }
    }
    __syncthreads();                                     // B4

    // ---- coalesced copy-out ----
    if (valid) {
        float4* og = (float4*)(outg + (size_t)win * 12288);
#pragma unroll
        for (int i = 0; i < 8; ++i)
            og[(srow + 8 * i) * 48 + scol] = *(const float4*)&of[(srow + 8 * i) * FSTR + scol * 4];
    }
}

extern "C" void kernel_launch(void* const* d_in, const int* in_sizes, int n_in,
                              void* d_out, int out_size, void* d_ws, size_t ws_size,
                              hipStream_t stream)
{
    const float* x          = (const float*)d_in[0];
    const float* wq         = (const float*)d_in[1];
    const float* bq         = (const float*)d_in[2];
    const float* wkv        = (const float*)d_in[3];
    const float* bkv        = (const float*)d_in[4];
    const float* bias_table = (const float*)d_in[5];
    const float* proj_w     = (const float*)d_in[6];
    const float* proj_b     = (const float*)d_in[7];
    float* out = (float*)d_out;

    int B = in_sizes[0] / (64 * 192);

    bf16*  wqkvT = (bf16*)d_ws;
    bf16*  projT = (bf16*)((char*)d_ws + 221184);
    float* biasB = (float*)((char*)d_ws + 294912);

    wattn_prep<<<672, 256, 0, stream>>>(wq, wkv, bias_table, proj_w, wqkvT, projT, biasB);

    wattn_main<<<(B + 1) / 2, 768, 0, stream>>>(x, wqkvT, bq, bkv, projT, biasB, proj_b, out, B);
}

// Round 8
// 241.764 us; speedup vs baseline: 1.6355x; 1.0706x over previous
//
#include <hip/hip_runtime.h>
#include <hip/hip_bf16.h>

typedef __bf16 bf16;
typedef bf16 bf16x8 __attribute__((ext_vector_type(8)));
typedef bf16 bf16x4 __attribute__((ext_vector_type(4)));
typedef short s16x4 __attribute__((ext_vector_type(4)));
typedef float f32x4 __attribute__((ext_vector_type(4)));

#define SCALE 0.17677669529663687f  // 1/sqrt(32)

// LDS: ONLY xb bf16 [64][208] = 26,624 B -> 2+ blocks/CU regardless of granularity.
#define XSTR 208
#define SMEM_ELEMS 13312

#if defined(__has_builtin)
#if __has_builtin(__builtin_amdgcn_mfma_f32_16x16x16bf16_1k)
#define HAS_MFMA16 1
#endif
#endif

// ---------------- prep kernel (unchanged, validated) ----------------
__global__ void wattn_prep(const float* __restrict__ wq, const float* __restrict__ wkv,
                           const float* __restrict__ bias_table, const float* __restrict__ proj_w,
                           bf16* __restrict__ wqkvT, bf16* __restrict__ projT,
                           float* __restrict__ biasB)
{
    int t = blockIdx.x * 256 + threadIdx.x;
    if (t < 110592) {                       // wqkvT[n][k] = W[k][n]
        int n = t / 192, k = t % 192;
        float v = (n < 192) ? wq[k * 192 + n] : wkv[k * 384 + (n - 192)];
        wqkvT[t] = (bf16)v;
    } else if (t < 147456) {                // projT[n][k] = proj_w[k][n]
        int e = t - 110592;
        int n = e / 192, k = e % 192;
        projT[e] = (bf16)proj_w[k * 192 + n];
    } else if (t < 172032) {                // biasB[h][m>>2][n][m&3]
        int e = t - 147456;
        int h  = e >> 12;
        int mb = (e >> 8) & 15;
        int n  = (e >> 2) & 63;
        int mr = e & 3;
        int m  = mb * 4 + mr;
        int idx = ((n & 7) - (m & 7) + 7) * 15 + ((n >> 3) - (m >> 3) + 7);
        biasB[e] = bias_table[idx * 6 + h];
    }
}

#if !defined(HAS_MFMA16)
// fallback: build K=32 frag from two D-layout bf16x4 tiles via shuffles
__device__ __forceinline__ bf16x8 build8(bf16x4 t0, bf16x4 t1, int li, int gi) {
    union { bf16x4 v; unsigned u[2]; } a0, a1;
    a0.v = t0; a1.v = t1;
    int b = li + 32 * (gi & 1);
    unsigned l0  = __shfl(a0.u[0], b),      l1  = __shfl(a0.u[1], b);
    unsigned l0h = __shfl(a0.u[0], b + 16), l1h = __shfl(a0.u[1], b + 16);
    unsigned h0  = __shfl(a1.u[0], b),      h1  = __shfl(a1.u[1], b);
    unsigned h0h = __shfl(a1.u[0], b + 16), h1h = __shfl(a1.u[1], b + 16);
    bool hi = (gi & 2);
    union { bf16x8 v8; unsigned u[4]; } r;
    r.u[0] = hi ? h0 : l0;   r.u[1] = hi ? h1 : l1;
    r.u[2] = hi ? h0h : l0h; r.u[3] = hi ? h1h : l1h;
    return r.v8;
}
#endif

// ---------------- fused main kernel: one window per block, one head per wave ----------------
// stage -> B1 -> passA(q,k; bias C-init) -> QK^T(bias C-init) -> softmax ->
// passB(v; bias C-init) -> PV -> B2 -> attn-out -> B3 -> proj(bias C-init) ->
// in-register 16x16 transpose -> direct coalesced f32 stores.  3 barriers, 26.6 KB LDS.
__global__ __launch_bounds__(384, 4)
void wattn_main(const float* __restrict__ x, const bf16* __restrict__ wqkvT,
                const float* __restrict__ bq, const float* __restrict__ bkv,
                const bf16* __restrict__ projT, const float* __restrict__ biasB,
                const float* __restrict__ proj_b, float* __restrict__ outg)
{
    __shared__ __align__(16) bf16 smem[SMEM_ELEMS];
    const int tid = threadIdx.x;
    const int li  = tid & 15;
    const int gi  = (tid >> 4) & 3;
    const int w   = tid >> 6;        // wave = head, 0..5
    const int win = blockIdx.x;

    bf16* xb = smem;
    const int srow = tid / 48, scol = tid % 48;
    const f32x4 fz = {0.f, 0.f, 0.f, 0.f};

    // ---- stage x: f32 global -> bf16 LDS [64][208] ----
    {
        const float4* xg = (const float4*)(x + (size_t)win * 12288);
#pragma unroll
        for (int i = 0; i < 8; ++i) {
            float4 p = xg[(srow + 8 * i) * 48 + scol];
            bf16x4 v; v[0]=(bf16)p.x; v[1]=(bf16)p.y; v[2]=(bf16)p.z; v[3]=(bf16)p.w;
            *(bf16x4*)&xb[(srow + 8 * i) * XSTR + scol * 4] = v;
        }
    }
    __syncthreads();                                     // B1

    // ======== pass A: q,k via TRANSPOSED GEMM; bias as accumulator init ========
    bf16x4 qf[2][4], kf[2][4];
    {
        f32x4 bjq0 = *(const f32x4*)&bq [32 * w + 4 * gi];
        f32x4 bjq1 = *(const f32x4*)&bq [32 * w + 16 + 4 * gi];
        f32x4 bjk0 = *(const f32x4*)&bkv[32 * w + 4 * gi];
        f32x4 bjk1 = *(const f32x4*)&bkv[32 * w + 16 + 4 * gi];
        f32x4 aqk[4][4];
#pragma unroll
        for (int c = 0; c < 4; ++c) {
            aqk[0][c] = bjq0; aqk[1][c] = bjq1;
            aqk[2][c] = bjk0; aqk[3][c] = bjk1;
        }
#pragma unroll 2
        for (int kk = 0; kk < 6; ++kk) {
            bf16x8 bx[4], aw[4];
#pragma unroll
            for (int c = 0; c < 4; ++c)
                bx[c] = *(const bf16x8*)&xb[(c * 16 + li) * XSTR + kk * 32 + gi * 8];
#pragma unroll
            for (int j = 0; j < 4; ++j) {
                int T = (j < 2) ? (2 * w + j) : (12 + 2 * w + (j - 2));
                aw[j] = *(const bf16x8*)&wqkvT[(size_t)(T * 16 + li) * 192 + kk * 32 + gi * 8];
            }
#pragma unroll
            for (int j = 0; j < 4; ++j)
#pragma unroll
                for (int c = 0; c < 4; ++c)
                    aqk[j][c] = __builtin_amdgcn_mfma_f32_16x16x32_bf16(aw[j], bx[c], aqk[j][c], 0, 0, 0);
        }
        // epilogue A: leaky (+SCALE for q) -> registers
#pragma unroll
        for (int j = 0; j < 2; ++j)
#pragma unroll
            for (int c = 0; c < 4; ++c) {
                bf16x4 rq, rk;
#pragma unroll
                for (int rg = 0; rg < 4; ++rg) {
                    float tq = aqk[j][c][rg];
                    float tk = aqk[2 + j][c][rg];
                    tq = (fmaxf(tq, 0.f) + 0.2f * fminf(tq, 0.f)) * SCALE;
                    tk =  fmaxf(tk, 0.f) + 0.2f * fminf(tk, 0.f);
                    rq[rg] = (bf16)tq;
                    rk[rg] = (bf16)tk;
                }
                qf[j][c] = rq;
                kf[j][c] = rk;
            }
    }

    // ======== QK^T from registers, rel-pos-bias as accumulator init ========
    f32x4 s[4][4];
#pragma unroll
    for (int cm = 0; cm < 4; ++cm)
#pragma unroll
        for (int cn = 0; cn < 4; ++cn) {
            f32x4 bv = *(const f32x4*)&biasB[w * 4096 + (4 * cm + gi) * 256 + (16 * cn + li) * 4];
#if defined(HAS_MFMA16)
            f32x4 t = __builtin_amdgcn_mfma_f32_16x16x16bf16_1k(
                __builtin_bit_cast(s16x4, kf[0][cm]), __builtin_bit_cast(s16x4, qf[0][cn]), bv, 0, 0, 0);
            s[cm][cn] = __builtin_amdgcn_mfma_f32_16x16x16bf16_1k(
                __builtin_bit_cast(s16x4, kf[1][cm]), __builtin_bit_cast(s16x4, qf[1][cn]), t, 0, 0, 0);
#else
            s[cm][cn] = __builtin_amdgcn_mfma_f32_16x16x32_bf16(
                build8(kf[0][cm], kf[1][cm], li, gi), build8(qf[0][cn], qf[1][cn], li, gi), bv, 0, 0, 0);
#endif
        }

    // ======== softmax over keys; s dies into pb ========
    float rs[4];
    bf16x4 pb[4][4];
#pragma unroll
    for (int cn = 0; cn < 4; ++cn) {
        float m_ = -1e30f;
#pragma unroll
        for (int cm = 0; cm < 4; ++cm)
#pragma unroll
            for (int rg = 0; rg < 4; ++rg) m_ = fmaxf(m_, s[cm][cn][rg]);
        m_ = fmaxf(m_, __shfl_xor(m_, 16));
        m_ = fmaxf(m_, __shfl_xor(m_, 32));
        float ss = 0.f;
#pragma unroll
        for (int cm = 0; cm < 4; ++cm) {
            bf16x4 r;
#pragma unroll
            for (int rg = 0; rg < 4; ++rg) {
                float p = __expf(s[cm][cn][rg] - m_);
                ss += p;
                r[rg] = (bf16)p;
            }
            pb[cm][cn] = r;
        }
        ss += __shfl_xor(ss, 16);
        ss += __shfl_xor(ss, 32);
        rs[cn] = 1.f / ss;
    }

    // ======== pass B: v via NORMAL GEMM; bias as accumulator init ========
    bf16x4 vf[2][4];   // [d-half][m-subtile]
    {
        f32x4 bjv0 = *(const f32x4*)&bkv[192 + 32 * w + 4 * gi];
        f32x4 bjv1 = *(const f32x4*)&bkv[192 + 32 * w + 16 + 4 * gi];
        f32x4 av_[4][2];
#pragma unroll
        for (int rt = 0; rt < 4; ++rt) { av_[rt][0] = bjv0; av_[rt][1] = bjv1; }
#pragma unroll 2
        for (int kk = 0; kk < 6; ++kk) {
            bf16x8 a[4], bwv[2];
#pragma unroll
            for (int rt = 0; rt < 4; ++rt)
                a[rt] = *(const bf16x8*)&xb[(rt * 16 + li) * XSTR + kk * 32 + gi * 8];
#pragma unroll
            for (int j = 0; j < 2; ++j)
                bwv[j] = *(const bf16x8*)&wqkvT[(size_t)((24 + 2 * w + j) * 16 + li) * 192 + kk * 32 + gi * 8];
#pragma unroll
            for (int rt = 0; rt < 4; ++rt)
#pragma unroll
                for (int j = 0; j < 2; ++j)
                    av_[rt][j] = __builtin_amdgcn_mfma_f32_16x16x32_bf16(a[rt], bwv[j], av_[rt][j], 0, 0, 0);
        }
#pragma unroll
        for (int j = 0; j < 2; ++j)
#pragma unroll
            for (int rt = 0; rt < 4; ++rt) {
                bf16x4 r;
#pragma unroll
                for (int rg = 0; rg < 4; ++rg) {
                    float t = av_[rt][j][rg];
                    t = fmaxf(t, 0.f) + 0.2f * fminf(t, 0.f);
                    r[rg] = (bf16)t;
                }
                vf[j][rt] = r;
            }
    }

    // ======== PV entirely from registers ========
    f32x4 o[2][4];
#pragma unroll
    for (int ct = 0; ct < 2; ++ct)
#pragma unroll
        for (int cn = 0; cn < 4; ++cn) {
#if defined(HAS_MFMA16)
            f32x4 t = fz;
#pragma unroll
            for (int rt = 0; rt < 4; ++rt)
                t = __builtin_amdgcn_mfma_f32_16x16x16bf16_1k(
                        __builtin_bit_cast(s16x4, vf[ct][rt]),
                        __builtin_bit_cast(s16x4, pb[rt][cn]), t, 0, 0, 0);
            o[ct][cn] = t;
#else
            f32x4 t = fz;
#pragma unroll
            for (int c = 0; c < 2; ++c)
                t = __builtin_amdgcn_mfma_f32_16x16x32_bf16(
                        build8(vf[ct][2 * c], vf[ct][2 * c + 1], li, gi),
                        build8(pb[2 * c][cn], pb[2 * c + 1][cn], li, gi), t, 0, 0, 0);
            o[ct][cn] = t;
#endif
        }
    __syncthreads();                                     // B2 (all xb reads done)

    // normalize + write attn-out [n][c] into xb
#pragma unroll
    for (int ct = 0; ct < 2; ++ct)
#pragma unroll
        for (int cn = 0; cn < 4; ++cn) {
            bf16x4 r;
#pragma unroll
            for (int rg = 0; rg < 4; ++rg) r[rg] = (bf16)(o[ct][cn][rg] * rs[cn]);
            *(bf16x4*)&xb[(cn * 16 + li) * XSTR + 32 * w + 16 * ct + 4 * gi] = r;
        }
    __syncthreads();                                     // B3 (attn-out complete)

    // ======== proj (transposed); proj_b as accumulator init ========
    f32x4 pa[2][4];
    {
        f32x4 pb0 = *(const f32x4*)&proj_b[32 * w + 4 * gi];
        f32x4 pb1 = *(const f32x4*)&proj_b[32 * w + 16 + 4 * gi];
#pragma unroll
        for (int cn = 0; cn < 4; ++cn) { pa[0][cn] = pb0; pa[1][cn] = pb1; }
    }
#pragma unroll 2
    for (int kk = 0; kk < 6; ++kk) {
        bf16x8 bo[4], awp[2];
#pragma unroll
        for (int cn = 0; cn < 4; ++cn)
            bo[cn] = *(const bf16x8*)&xb[(cn * 16 + li) * XSTR + kk * 32 + gi * 8];
#pragma unroll
        for (int ct = 0; ct < 2; ++ct)
            awp[ct] = *(const bf16x8*)&projT[(size_t)((2 * w + ct) * 16 + li) * 192 + kk * 32 + gi * 8];
#pragma unroll
        for (int ct = 0; ct < 2; ++ct)
#pragma unroll
            for (int cn = 0; cn < 4; ++cn)
                pa[ct][cn] = __builtin_amdgcn_mfma_f32_16x16x32_bf16(awp[ct], bo[cn], pa[ct][cn], 0, 0, 0);
    }

    // ======== in-register 16x16 transpose (4 shfl/tile) + direct coalesced f32x4 stores ====
    // dest lane L: token = 16cn + (L>>2), features 32w+16ct+4*(L&3)+e.
    // element (r,c) sits at src lane c+16*(r>>2), reg r&3 -> src = (L>>2)+16*(L&3), reg e.
    {
        const int L = tid & 63;
        const int src = (L >> 2) + 16 * (L & 3);
        f32x4* og = (f32x4*)(outg + (size_t)win * 12288);
#pragma unroll
        for (int cn = 0; cn < 4; ++cn)
#pragma unroll
            for (int ct = 0; ct < 2; ++ct) {       // ct inner: both 64B halves of a line back-to-back
                f32x4 y;
#pragma unroll
                for (int e = 0; e < 4; ++e)
                    y[e] = __shfl(pa[ct][cn][e], src);
                og[(16 * cn + (L >> 2)) * 48 + 8 * w + 4 * ct + (L & 3)] = y;
            }
    }
}

extern "C" void kernel_launch(void* const* d_in, const int* in_sizes, int n_in,
                              void* d_out, int out_size, void* d_ws, size_t ws_size,
                              hipStream_t stream)
{
    const float* x          = (const float*)d_in[0];
    const float* wq         = (const float*)d_in[1];
    const float* bq         = (const float*)d_in[2];
    const float* wkv        = (const float*)d_in[3];
    const float* bkv        = (const float*)d_in[4];
    const float* bias_table = (const float*)d_in[5];
    const float* proj_w     = (const float*)d_in[6];
    const float* proj_b     = (const float*)d_in[7];
    float* out = (float*)d_out;

    int B = in_sizes[0] / (64 * 192);

    bf16*  wqkvT = (bf16*)d_ws;
    bf16*  projT = (bf16*)((char*)d_ws + 221184);
    float* biasB = (float*)((char*)d_ws + 294912);

    wattn_prep<<<672, 256, 0, stream>>>(wq, wkv, bias_table, proj_w, wqkvT, projT, biasB);

    wattn_main<<<B, 384, 0, stream>>>(x, wqkvT, bq, bkv, projT, biasB, proj_b, out);
}